// Round 18
// baseline (493.500 us; speedup 1.0000x reference)
//
#include <hip/hip_runtime.h>

#define T_TOK 8192
#define DDIM 1024
#define HDIM 2048
#define NEXP 8

typedef __attribute__((ext_vector_type(8))) short short8;
typedef __attribute__((ext_vector_type(4))) float f32x4;

#define WAITV8 asm volatile("s_waitcnt vmcnt(8)" ::: "memory")
#define WAITV6 asm volatile("s_waitcnt vmcnt(6)" ::: "memory")
#define WAITV0 asm volatile("s_waitcnt vmcnt(0)" ::: "memory")
#define WAITL0 asm volatile("s_waitcnt lgkmcnt(0)" ::: "memory")
#define BARRIER __builtin_amdgcn_s_barrier()

__device__ __forceinline__ unsigned short f2bf(float f) {
  unsigned int u = __builtin_bit_cast(unsigned int, f);
  u += 0x7fffu + ((u >> 16) & 1u);   // RNE
  return (unsigned short)(u >> 16);
}
__device__ __forceinline__ float bf2f(unsigned short h) {
  unsigned int u = ((unsigned int)h) << 16;
  return __builtin_bit_cast(float, u);
}
__device__ __forceinline__ void gload16(const void* g, void* l) {
  __builtin_amdgcn_global_load_lds((const __attribute__((address_space(1))) void*)g,
                                   (__attribute__((address_space(3))) void*)l, 16, 0, 0);
}
__device__ __forceinline__ int imin(int a, int b) { return a < b ? a : b; }

// ------- merged fp32 -> bf16 transpose-convert for w1/w2/w3 (one dispatch) -------
// grid dim3(32,16,24): z<8 w1 (perm,s16=0), z<16 w2 (perm,s16=16), else w3 (no perm).
__global__ __launch_bounds__(256) void tcvt_all_kernel(const float* __restrict__ w1,
                                                       const float* __restrict__ w2,
                                                       const float* __restrict__ w3,
                                                       unsigned short* __restrict__ w12t,
                                                       unsigned short* __restrict__ w3t) {
  int z = blockIdx.z;
  const float* inE; unsigned short* outE;
  int R, C, perm, s16, rb, cb;
  if (z < 16) {
    int e = z & 7;
    inE = (z < 8 ? w1 : w2) + (size_t)e * 1024 * 2048;
    outE = w12t + (size_t)e * 4096 * 1024;
    R = 1024; C = 2048; perm = 1; s16 = (z < 8) ? 0 : 16;
    rb = blockIdx.y * 64; cb = blockIdx.x * 64;
  } else {
    int e = z - 16;
    inE = w3 + (size_t)e * 2048 * 1024;
    outE = w3t + (size_t)e * 1024 * 2048;
    R = 2048; C = 1024; perm = 0; s16 = 0;
    rb = blockIdx.x * 64; cb = blockIdx.y * 64;   // swapped roles (R=2048 needs 32)
  }
  __shared__ float tile[64][65];
  int tid = threadIdx.x;
  #pragma unroll
  for (int i = 0; i < 4; ++i) {
    int f = tid + i * 256;
    int r = f >> 4, c4 = (f & 15) << 2;
    float4 v = *(const float4*)(inE + (size_t)(rb + r) * C + cb + c4);
    tile[r][c4] = v.x; tile[r][c4 + 1] = v.y; tile[r][c4 + 2] = v.z; tile[r][c4 + 3] = v.w;
  }
  __syncthreads();
  #pragma unroll
  for (int i = 0; i < 2; ++i) {
    int g = tid + i * 256;
    int oc = g >> 3;
    int r8 = (g & 7) << 3;
    alignas(16) unsigned short tmp[8];
    #pragma unroll
    for (int j = 0; j < 8; ++j) tmp[j] = f2bf(tile[r8 + j][oc]);
    int orow = cb + oc;
    int orow2 = perm ? (32 * (orow >> 4) + (orow & 15) + s16) : orow;
    *(uint4*)(outE + (size_t)orow2 * R + rb + r8) = *(const uint4*)tmp;
  }
}

// ------- gating: logits, softmax, top-2 + fused x->bf16 convert (NO atomics) -------
__global__ __launch_bounds__(256) void gate_kernel(const float* __restrict__ x,
                                                   const float* __restrict__ gw,
                                                   int* __restrict__ t_exp,
                                                   float* __restrict__ t_w,
                                                   unsigned short* __restrict__ xbf) {
  int t = blockIdx.x * 4 + (threadIdx.x >> 6);
  int lane = threadIdx.x & 63;
  const float* xp = x + (size_t)t * DDIM;
  unsigned short* xo = xbf + (size_t)t * DDIM;
  float acc[NEXP];
  #pragma unroll
  for (int e = 0; e < NEXP; ++e) acc[e] = 0.f;
  for (int i = 0; i < DDIM / 64; ++i) {
    int d = i * 64 + lane;
    float xv = xp[d];
    xo[d] = f2bf(xv);
    const float* g = gw + d * NEXP;
    #pragma unroll
    for (int e = 0; e < NEXP; ++e) acc[e] += xv * g[e];
  }
  #pragma unroll
  for (int off = 32; off > 0; off >>= 1) {
    #pragma unroll
    for (int e = 0; e < NEXP; ++e) acc[e] += __shfl_xor(acc[e], off, 64);
  }
  float mx = acc[0];
  #pragma unroll
  for (int e = 1; e < NEXP; ++e) mx = fmaxf(mx, acc[e]);
  float p[NEXP]; float S = 0.f;
  #pragma unroll
  for (int e = 0; e < NEXP; ++e) { p[e] = expf(acc[e] - mx); S += p[e]; }
  int i0 = 0; float v0 = p[0];
  #pragma unroll
  for (int e = 1; e < NEXP; ++e) if (p[e] > v0) { v0 = p[e]; i0 = e; }
  int i1 = -1; float v1 = -1.f;
  #pragma unroll
  for (int e = 0; e < NEXP; ++e) if (e != i0 && p[e] > v1) { v1 = p[e]; i1 = e; }
  float pv0 = v0 / S, pv1 = v1 / S;
  float denom = pv0 + pv1 + 1e-9f;
  if (lane == 0) {
    t_exp[t * 2] = i0; t_exp[t * 2 + 1] = i1;
    t_w[t * 2] = pv0 / denom; t_w[t * 2 + 1] = pv1 / denom;
  }
}

// -------- deterministic partition + dynamic tile maps + tickets (NO atomics) ----
// ctrl: [0..8) counts, [8..16) offsets, [16]=T1(256-tiles), [17]=T2(128-tiles),
//       [18]=gemm1 ticket, [19]=gemm2 ticket.
// tmap (dead t_exp buffer): [0..72) 256-tile map, [128..264) 128-tile map.
__global__ __launch_bounds__(1024) void partition_kernel(
    const int* __restrict__ t_exp, const float* __restrict__ t_w,
    int* __restrict__ ctrl, int* __restrict__ row_tok,
    float* __restrict__ row_w, int* __restrict__ inv_row,
    int* __restrict__ tmap) {
  int tid = threadIdx.x;
  int wv = tid >> 6, lane = tid & 63;
  __shared__ int wtot[16][8];
  __shared__ int wbase[16][8];
  __shared__ int soff[8];

  int t0 = tid * 8;
  int exps[16];
  int c[8];
  #pragma unroll
  for (int e = 0; e < 8; ++e) c[e] = 0;
  #pragma unroll
  for (int s = 0; s < 16; ++s) {
    exps[s] = t_exp[t0 * 2 + s];
    #pragma unroll
    for (int e = 0; e < 8; ++e) c[e] += (exps[s] == e);
  }
  int inc[8];
  #pragma unroll
  for (int e = 0; e < 8; ++e) inc[e] = c[e];
  #pragma unroll
  for (int d = 1; d < 64; d <<= 1) {
    #pragma unroll
    for (int e = 0; e < 8; ++e) {
      int v = __shfl_up(inc[e], d, 64);
      if (lane >= d) inc[e] += v;
    }
  }
  if (lane == 63) {
    #pragma unroll
    for (int e = 0; e < 8; ++e) wtot[wv][e] = inc[e];
  }
  __syncthreads();
  if (wv == 0 && lane < 16) {
    #pragma unroll
    for (int e = 0; e < 8; ++e) {
      int b = 0;
      for (int w = 0; w < 16; ++w)
        if (w < lane) b += wtot[w][e];
      wbase[lane][e] = b;
    }
  }
  __syncthreads();
  if (tid == 0) {
    int o = 0;
    #pragma unroll
    for (int e = 0; e < 8; ++e) {
      int tot = wbase[15][e] + wtot[15][e];
      ctrl[e] = tot; ctrl[8 + e] = o; soff[e] = o; o += tot;
    }
  }
  __syncthreads();
  int base[8];
  #pragma unroll
  for (int e = 0; e < 8; ++e) base[e] = soff[e] + wbase[wv][e] + (inc[e] - c[e]);
  #pragma unroll
  for (int s = 0; s < 16; ++s) {
    int ee = exps[s];
    float w = t_w[t0 * 2 + s];
    int pos = 0;
    #pragma unroll
    for (int e = 0; e < 8; ++e)
      if (ee == e) { pos = base[e]; base[e] = base[e] + 1; }
    row_tok[pos] = t0 + (s >> 1);
    row_w[pos] = w;
    inv_row[t0 * 2 + s] = pos;
  }
  __syncthreads();
  // parallel tile-map build: lane e of wave 0 writes expert e's entries
  if (wv == 0 && lane < 8) {
    int cnt = ctrl[lane];
    int n1 = (cnt + 255) >> 8, n2 = (cnt + 127) >> 7;
    int p1 = n1, p2 = n2;
    #pragma unroll
    for (int d = 1; d < 8; d <<= 1) {
      int v1 = __shfl_up(p1, d, 64);
      int v2 = __shfl_up(p2, d, 64);
      if (lane >= d) { p1 += v1; p2 += v2; }
    }
    int b1 = p1 - n1, b2 = p2 - n2;
    for (int m = 0; m < n1; ++m) tmap[b1 + m] = (lane << 8) | m;
    for (int m = 0; m < n2; ++m) tmap[128 + b2 + m] = (lane << 8) | m;
    if (lane == 7) { ctrl[16] = p1; ctrl[17] = p2; ctrl[18] = 0; ctrl[19] = 0; }
  }
}

// ====== grouped GEMM, BK=32 tiles, 4-deep rotation, ONE barrier/tile (R14) ======
// Persistent blocks: grid 256 (1 block/CU), work items drawn from an atomic ticket.
// Deterministic: tile outputs independent of which CU computes them.

#define KSTEP(T_, NT_) do {                                                \
    int buf_ = (T_) & 3;                                                   \
    WAITV8;                                                                \
    BARRIER;                                                               \
    int tc_ = imin((T_) + 3, (NT_) - 1);                                   \
    STG(tc_ & 3, tc_);                                                     \
    short8 av[8], bv[4];                                                   \
    _Pragma("unroll")                                                      \
    for (int n = 0; n < 4; ++n)                                            \
      bv[n] = *(const short8*)(&lds[buf_][1][0] + bOff + n * 512);         \
    _Pragma("unroll")                                                      \
    for (int m = 0; m < 8; ++m)                                            \
      av[m] = *(const short8*)(&lds[buf_][0][0] + aOff + m * 512);         \
    __builtin_amdgcn_s_setprio(1);                                         \
    _Pragma("unroll")                                                      \
    for (int m = 0; m < 8; ++m)                                            \
      _Pragma("unroll")                                                    \
      for (int n = 0; n < 4; ++n)                                          \
        acc[m][n] = __builtin_amdgcn_mfma_f32_16x16x32_bf16(av[m], bv[n], acc[m][n], 0, 0, 0); \
    __builtin_amdgcn_s_setprio(0);                                         \
    WAITL0;                                                                \
} while (0)

#define K_PIPELINE(NT_)                                                    \
  WAITV0;                                                                  \
  STG(0, 0); STG(1, 1); STG(2, 2);                                         \
  _Pragma("unroll 1")                                                      \
  for (int t = 0; t < (NT_); ++t) { KSTEP(t, (NT_)); }

// ---------------- GEMM1: 256x256 tiles, persistent ticket blocks ----------------
__global__ __launch_bounds__(512, 1) void gemm1_kernel(
    const unsigned short* __restrict__ xbf,   // [T][1024]
    const unsigned short* __restrict__ w12t,  // [E][4096][1024], 16-row interleave
    const int* __restrict__ row_tok, const float* __restrict__ row_w,
    int* __restrict__ ctrl, const int* __restrict__ tmap,
    unsigned short* __restrict__ G) {
  __shared__ unsigned short lds[4][2][8192];  // [depth][A/B][256 rows * 32 K]
  __shared__ int s_item;

  int tid = threadIdx.x, lane = tid & 63;
  int sr = tid >> 2;
  int cS8 = ((tid & 3) ^ ((sr >> 1) & 3)) * 8;
  int wid = tid >> 6, wr = wid >> 2, wc = wid & 3;
  int lr16 = lane & 15, hi = lane >> 4;
  int koff = (hi ^ ((lr16 >> 1) & 3)) * 8;
  int aOff = (wr * 128 + lr16) * 32 + koff;
  int bOff = (wc * 64 + lr16) * 32 + koff;
  int total = ctrl[16] << 4;                  // T1 * 16 nt

  for (;;) {
    BARRIER;                                  // all waves done with LDS of prev item
    if (tid == 0) s_item = atomicAdd(&ctrl[18], 1);
    BARRIER;
    int item = s_item;
    if (item >= total) break;
    int nt = item & 15, ti = item >> 4;
    int pm = tmap[ti];
    int e = pm >> 8, mt = pm & 255;
    int cnt = ctrl[e];
    int off = ctrl[8 + e];

    const unsigned short* w12e = w12t + (size_t)e * (4096 * 1024);
    const unsigned short* bQ0 = w12e + (size_t)(nt * 256 + sr) * 1024 + cS8;
    const unsigned short* bQ1 = w12e + (size_t)(nt * 256 + 128 + sr) * 1024 + cS8;
    int tokA = row_tok[off + imin(mt * 256 + sr, cnt - 1)];
    int tokB = row_tok[off + imin(mt * 256 + 128 + sr, cnt - 1)];
    const unsigned short* aQ0 = xbf + (size_t)tokA * 1024 + cS8;
    const unsigned short* aQ1 = xbf + (size_t)tokB * 1024 + cS8;

#define STG(SB, T_) do {                                                   \
    gload16(aQ0 + (T_) * 32, &lds[SB][0][0] + tid * 8);                    \
    gload16(aQ1 + (T_) * 32, &lds[SB][0][0] + 4096 + tid * 8);             \
    gload16(bQ0 + (T_) * 32, &lds[SB][1][0] + tid * 8);                    \
    gload16(bQ1 + (T_) * 32, &lds[SB][1][0] + 4096 + tid * 8); } while (0)

    f32x4 z = {0.f, 0.f, 0.f, 0.f};
    f32x4 acc[8][4];
    #pragma unroll
    for (int m = 0; m < 8; ++m)
      #pragma unroll
      for (int n = 0; n < 4; ++n) acc[m][n] = z;

    K_PIPELINE(32)

    // fused SwiGLU epilogue: frag pairs (0,1),(2,3) are (W1,W2) for same H cols
    #pragma unroll
    for (int m = 0; m < 8; ++m)
      #pragma unroll
      for (int jj = 0; jj < 4; ++jj) {
        int rl = mt * 256 + wr * 128 + m * 16 + hi * 4 + jj;
        if (rl < cnt) {
          float wrj = row_w[off + rl];
          size_t base = (size_t)(off + rl) * HDIM + nt * 128 + wc * 32 + lr16;
          float h1 = acc[m][0][jj], h2 = acc[m][1][jj];
          G[base] = f2bf((h1 / (1.f + __expf(-h1))) * h2 * wrj);
          h1 = acc[m][2][jj]; h2 = acc[m][3][jj];
          G[base + 16] = f2bf((h1 / (1.f + __expf(-h1))) * h2 * wrj);
        }
      }
#undef STG
  }
}

// ---------------- GEMM2: 128x256 tiles, persistent ticket blocks ----------------
__global__ __launch_bounds__(512, 1) void gemm2_kernel(
    const unsigned short* __restrict__ G,     // [16384][2048]
    const unsigned short* __restrict__ w3t,   // [E][1024][2048]
    int* __restrict__ ctrl, const int* __restrict__ tmap,
    unsigned short* __restrict__ Y) {
  __shared__ unsigned short ldsA[4][4096];   // 128 rows * 32 K
  __shared__ unsigned short ldsB[4][8192];   // 256 rows * 32 K
  __shared__ int s_item;

  int tid = threadIdx.x, lane = tid & 63;
  int sr = tid >> 2;
  int cS8 = ((tid & 3) ^ ((sr >> 1) & 3)) * 8;
  int wid = tid >> 6, wr = wid >> 2, wc = wid & 3;   // wr 0..1, wc 0..3
  int lr16 = lane & 15, hi = lane >> 4;
  int koff = (hi ^ ((lr16 >> 1) & 3)) * 8;
  int aOff = (wr * 64 + lr16) * 32 + koff;
  int bOff = (wc * 64 + lr16) * 32 + koff;
  int total = ctrl[17] << 2;                  // T2 * 4 nt

  for (;;) {
    BARRIER;
    if (tid == 0) s_item = atomicAdd(&ctrl[19], 1);
    BARRIER;
    int item = s_item;
    if (item >= total) break;
    int nt = item & 3, ti = item >> 2;
    int pm = tmap[ti];
    int e = pm >> 8, mt = pm & 255;           // M=128 tile index
    int cnt = ctrl[e];
    int off = ctrl[8 + e];

    const unsigned short* w3e = w3t + (size_t)e * (1024 * 2048);
    const unsigned short* bQ0 = w3e + (size_t)(nt * 256 + sr) * 2048 + cS8;
    const unsigned short* bQ1 = w3e + (size_t)(nt * 256 + 128 + sr) * 2048 + cS8;
    const unsigned short* aQ0 =
        G + (size_t)(off + imin(mt * 128 + sr, cnt - 1)) * 2048 + cS8;

#define STG2(SB, T_) do {                                                  \
    gload16(aQ0 + (T_) * 32, &ldsA[SB][0] + tid * 8);                      \
    gload16(bQ0 + (T_) * 32, &ldsB[SB][0] + tid * 8);                      \
    gload16(bQ1 + (T_) * 32, &ldsB[SB][0] + 4096 + tid * 8); } while (0)

    f32x4 z = {0.f, 0.f, 0.f, 0.f};
    f32x4 acc[4][4];
    #pragma unroll
    for (int m = 0; m < 4; ++m)
      #pragma unroll
      for (int n = 0; n < 4; ++n) acc[m][n] = z;

    WAITV0;
    STG2(0, 0); STG2(1, 1); STG2(2, 2);
    #pragma unroll 1
    for (int t = 0; t < 64; ++t) {
      int buf = t & 3;
      WAITV6;
      BARRIER;
      int tc = imin(t + 3, 63);
      STG2(tc & 3, tc);
      short8 av[4], bv[4];
      #pragma unroll
      for (int n = 0; n < 4; ++n)
        bv[n] = *(const short8*)(&ldsB[buf][0] + bOff + n * 512);
      #pragma unroll
      for (int m = 0; m < 4; ++m)
        av[m] = *(const short8*)(&ldsA[buf][0] + aOff + m * 512);
      __builtin_amdgcn_s_setprio(1);
      #pragma unroll
      for (int m = 0; m < 4; ++m)
        #pragma unroll
        for (int n = 0; n < 4; ++n)
          acc[m][n] = __builtin_amdgcn_mfma_f32_16x16x32_bf16(av[m], bv[n], acc[m][n], 0, 0, 0);
      __builtin_amdgcn_s_setprio(0);
      WAITL0;
    }
#undef STG2

    #pragma unroll
    for (int m = 0; m < 4; ++m)
      #pragma unroll
      for (int jj = 0; jj < 4; ++jj) {
        int rl = mt * 128 + wr * 64 + m * 16 + hi * 4 + jj;
        if (rl < cnt) {
          size_t yrow = (size_t)(off + rl) * DDIM + nt * 256 + wc * 64 + lr16;
          #pragma unroll
          for (int n = 0; n < 4; ++n) Y[yrow + n * 16] = f2bf(acc[m][n][jj]);
        }
      }
  }
}

// ---------------- combine: out[t] = Y[rowA] + Y[rowB] ----------------
__global__ __launch_bounds__(256) void combine_kernel(const unsigned short* __restrict__ Y,
                                                      const int* __restrict__ inv_row,
                                                      float* __restrict__ out) {
  int gid = blockIdx.x * 256 + threadIdx.x;   // 8192 * 128
  int t = gid >> 7;
  int cidx = (gid & 127) * 8;
  int rA = inv_row[t * 2], rB = inv_row[t * 2 + 1];
  uint4 va = *(const uint4*)(Y + (size_t)rA * DDIM + cidx);
  uint4 vb = *(const uint4*)(Y + (size_t)rB * DDIM + cidx);
  const unsigned short* pa = (const unsigned short*)&va;
  const unsigned short* pb = (const unsigned short*)&vb;
  float4 o0, o1;
  o0.x = bf2f(pa[0]) + bf2f(pb[0]); o0.y = bf2f(pa[1]) + bf2f(pb[1]);
  o0.z = bf2f(pa[2]) + bf2f(pb[2]); o0.w = bf2f(pa[3]) + bf2f(pb[3]);
  o1.x = bf2f(pa[4]) + bf2f(pb[4]); o1.y = bf2f(pa[5]) + bf2f(pb[5]);
  o1.z = bf2f(pa[6]) + bf2f(pb[6]); o1.w = bf2f(pa[7]) + bf2f(pb[7]);
  float* op = out + (size_t)t * DDIM + cidx;
  *(float4*)op = o0;
  *(float4*)(op + 4) = o1;
}

extern "C" void kernel_launch(void* const* d_in, const int* in_sizes, int n_in,
                              void* d_out, int out_size, void* d_ws, size_t ws_size,
                              hipStream_t stream) {
  const float* x  = (const float*)d_in[0];
  const float* gw = (const float*)d_in[1];
  const float* w1 = (const float*)d_in[2];
  const float* w2 = (const float*)d_in[3];
  const float* w3 = (const float*)d_in[4];
  float* out = (float*)d_out;
  char* ws = (char*)d_ws;

  // workspace layout (bytes); total ~218.4 MB
  unsigned short* xbf  = (unsigned short*)(ws + 0);             // 16,777,216
  unsigned short* w12t = (unsigned short*)(ws + 16777216);      // 67,108,864
  unsigned short* w3t  = (unsigned short*)(ws + 83886080);      // 33,554,432
  unsigned short* G    = (unsigned short*)(ws + 117440512);     // 67,108,864
  unsigned short* Y    = (unsigned short*)(ws + 184549376);     // 33,554,432
  int*   row_tok = (int*)  (ws + 218103808);
  float* row_w   = (float*)(ws + 218169344);
  int*   inv_row = (int*)  (ws + 218234880);
  int*   t_exp   = (int*)  (ws + 218300416);   // reused as tmap after partition
  float* t_w     = (float*)(ws + 218365952);
  int*   ctrl    = (int*)  (ws + 218431488);

  tcvt_all_kernel<<<dim3(32, 16, 24), 256, 0, stream>>>(w1, w2, w3, w12t, w3t);

  gate_kernel<<<2048, 256, 0, stream>>>(x, gw, t_exp, t_w, xbf);
  partition_kernel<<<1, 1024, 0, stream>>>(t_exp, t_w, ctrl, row_tok, row_w,
                                           inv_row, t_exp);

  gemm1_kernel<<<256, 512, 0, stream>>>(xbf, w12t, row_tok, row_w, ctrl, t_exp, G);
  gemm2_kernel<<<256, 512, 0, stream>>>(G, w3t, ctrl, t_exp + 128, Y);
  combine_kernel<<<4096, 256, 0, stream>>>(Y, inv_row, out);
}

// Round 19
// 434.497 us; speedup vs baseline: 1.1358x; 1.1358x over previous
//
#include <hip/hip_runtime.h>

#define T_TOK 8192
#define DDIM 1024
#define HDIM 2048
#define NEXP 8

typedef __attribute__((ext_vector_type(8))) short short8;
typedef __attribute__((ext_vector_type(4))) float f32x4;

#define WAITV8 asm volatile("s_waitcnt vmcnt(8)" ::: "memory")
#define WAITV6 asm volatile("s_waitcnt vmcnt(6)" ::: "memory")
#define WAITV0 asm volatile("s_waitcnt vmcnt(0)" ::: "memory")
#define WAITL0 asm volatile("s_waitcnt lgkmcnt(0)" ::: "memory")
#define BARRIER __builtin_amdgcn_s_barrier()

__device__ __forceinline__ unsigned short f2bf(float f) {
  unsigned int u = __builtin_bit_cast(unsigned int, f);
  u += 0x7fffu + ((u >> 16) & 1u);   // RNE
  return (unsigned short)(u >> 16);
}
__device__ __forceinline__ float bf2f(unsigned short h) {
  unsigned int u = ((unsigned int)h) << 16;
  return __builtin_bit_cast(float, u);
}
__device__ __forceinline__ void gload16(const void* g, void* l) {
  __builtin_amdgcn_global_load_lds((const __attribute__((address_space(1))) void*)g,
                                   (__attribute__((address_space(3))) void*)l, 16, 0, 0);
}
__device__ __forceinline__ int imin(int a, int b) { return a < b ? a : b; }

// ------- fused prep: weight transpose-converts (bid<12288) + gate (bid>=12288) -------
// tcvt part: zz = bid/(32*16): zz<8 w1(perm,s16=0), zz<16 w2(perm,16), else w3(no perm)
__global__ __launch_bounds__(256) void prep_kernel(const float* __restrict__ x,
                                                   const float* __restrict__ gw,
                                                   const float* __restrict__ w1,
                                                   const float* __restrict__ w2,
                                                   const float* __restrict__ w3,
                                                   unsigned short* __restrict__ w12t,
                                                   unsigned short* __restrict__ w3t,
                                                   int* __restrict__ t_exp,
                                                   float* __restrict__ t_w,
                                                   unsigned short* __restrict__ xbf) {
  int bid = blockIdx.x;
  int tid = threadIdx.x;
  if (bid < 12288) {
    int z = bid >> 9;                 // /(32*16)
    int rem = bid & 511;
    int by = rem >> 5, bx = rem & 31; // by<16, bx<32
    const float* inE; unsigned short* outE;
    int R, C, perm, s16, rb, cb;
    if (z < 16) {
      int e = z & 7;
      inE = (z < 8 ? w1 : w2) + (size_t)e * 1024 * 2048;
      outE = w12t + (size_t)e * 4096 * 1024;
      R = 1024; C = 2048; perm = 1; s16 = (z < 8) ? 0 : 16;
      rb = by * 64; cb = bx * 64;
    } else {
      int e = z - 16;
      inE = w3 + (size_t)e * 2048 * 1024;
      outE = w3t + (size_t)e * 1024 * 2048;
      R = 2048; C = 1024; perm = 0; s16 = 0;
      rb = bx * 64; cb = by * 64;
    }
    __shared__ float tile[64][65];
    #pragma unroll
    for (int i = 0; i < 4; ++i) {
      int f = tid + i * 256;
      int r = f >> 4, c4 = (f & 15) << 2;
      float4 v = *(const float4*)(inE + (size_t)(rb + r) * C + cb + c4);
      tile[r][c4] = v.x; tile[r][c4 + 1] = v.y; tile[r][c4 + 2] = v.z; tile[r][c4 + 3] = v.w;
    }
    __syncthreads();
    #pragma unroll
    for (int i = 0; i < 2; ++i) {
      int g = tid + i * 256;
      int oc = g >> 3;
      int r8 = (g & 7) << 3;
      alignas(16) unsigned short tmp[8];
      #pragma unroll
      for (int j = 0; j < 8; ++j) tmp[j] = f2bf(tile[r8 + j][oc]);
      int orow = cb + oc;
      int orow2 = perm ? (32 * (orow >> 4) + (orow & 15) + s16) : orow;
      *(uint4*)(outE + (size_t)orow2 * R + rb + r8) = *(const uint4*)tmp;
    }
  } else {
    int gb = bid - 12288;             // 0..2047
    int t = gb * 4 + (tid >> 6);
    int lane = tid & 63;
    const float* xp = x + (size_t)t * DDIM;
    unsigned short* xo = xbf + (size_t)t * DDIM;
    float acc[NEXP];
    #pragma unroll
    for (int e = 0; e < NEXP; ++e) acc[e] = 0.f;
    for (int i = 0; i < DDIM / 64; ++i) {
      int d = i * 64 + lane;
      float xv = xp[d];
      xo[d] = f2bf(xv);
      const float* g = gw + d * NEXP;
      #pragma unroll
      for (int e = 0; e < NEXP; ++e) acc[e] += xv * g[e];
    }
    #pragma unroll
    for (int off = 32; off > 0; off >>= 1) {
      #pragma unroll
      for (int e = 0; e < NEXP; ++e) acc[e] += __shfl_xor(acc[e], off, 64);
    }
    float mx = acc[0];
    #pragma unroll
    for (int e = 1; e < NEXP; ++e) mx = fmaxf(mx, acc[e]);
    float p[NEXP]; float S = 0.f;
    #pragma unroll
    for (int e = 0; e < NEXP; ++e) { p[e] = expf(acc[e] - mx); S += p[e]; }
    int i0 = 0; float v0 = p[0];
    #pragma unroll
    for (int e = 1; e < NEXP; ++e) if (p[e] > v0) { v0 = p[e]; i0 = e; }
    int i1 = -1; float v1 = -1.f;
    #pragma unroll
    for (int e = 0; e < NEXP; ++e) if (e != i0 && p[e] > v1) { v1 = p[e]; i1 = e; }
    float pv0 = v0 / S, pv1 = v1 / S;
    float denom = pv0 + pv1 + 1e-9f;
    if (lane == 0) {
      t_exp[t * 2] = i0; t_exp[t * 2 + 1] = i1;
      t_w[t * 2] = pv0 / denom; t_w[t * 2 + 1] = pv1 / denom;
    }
  }
}

// -------- deterministic partition + dynamic tile maps (NO atomics) ----
// ctrl: [0..8) counts, [8..16) offsets, [16]=T1(256-tiles), [17]=T2(128-tiles).
// tmap (dead t_exp buffer): [0..72) 256-tile map, [128..264) 128-tile map.
__global__ __launch_bounds__(1024) void partition_kernel(
    const int* __restrict__ t_exp, const float* __restrict__ t_w,
    int* __restrict__ ctrl, int* __restrict__ row_tok,
    float* __restrict__ row_w, int* __restrict__ inv_row,
    int* __restrict__ tmap) {
  int tid = threadIdx.x;
  int wv = tid >> 6, lane = tid & 63;
  __shared__ int wtot[16][8];
  __shared__ int wbase[16][8];
  __shared__ int soff[8];

  int t0 = tid * 8;
  int exps[16];
  int c[8];
  #pragma unroll
  for (int e = 0; e < 8; ++e) c[e] = 0;
  #pragma unroll
  for (int s = 0; s < 16; ++s) {
    exps[s] = t_exp[t0 * 2 + s];
    #pragma unroll
    for (int e = 0; e < 8; ++e) c[e] += (exps[s] == e);
  }
  int inc[8];
  #pragma unroll
  for (int e = 0; e < 8; ++e) inc[e] = c[e];
  #pragma unroll
  for (int d = 1; d < 64; d <<= 1) {
    #pragma unroll
    for (int e = 0; e < 8; ++e) {
      int v = __shfl_up(inc[e], d, 64);
      if (lane >= d) inc[e] += v;
    }
  }
  if (lane == 63) {
    #pragma unroll
    for (int e = 0; e < 8; ++e) wtot[wv][e] = inc[e];
  }
  __syncthreads();
  if (wv == 0 && lane < 16) {
    #pragma unroll
    for (int e = 0; e < 8; ++e) {
      int b = 0;
      for (int w = 0; w < 16; ++w)
        if (w < lane) b += wtot[w][e];
      wbase[lane][e] = b;
    }
  }
  __syncthreads();
  if (tid == 0) {
    int o = 0;
    #pragma unroll
    for (int e = 0; e < 8; ++e) {
      int tot = wbase[15][e] + wtot[15][e];
      ctrl[e] = tot; ctrl[8 + e] = o; soff[e] = o; o += tot;
    }
  }
  __syncthreads();
  int base[8];
  #pragma unroll
  for (int e = 0; e < 8; ++e) base[e] = soff[e] + wbase[wv][e] + (inc[e] - c[e]);
  #pragma unroll
  for (int s = 0; s < 16; ++s) {
    int ee = exps[s];
    float w = t_w[t0 * 2 + s];
    int pos = 0;
    #pragma unroll
    for (int e = 0; e < 8; ++e)
      if (ee == e) { pos = base[e]; base[e] = base[e] + 1; }
    row_tok[pos] = t0 + (s >> 1);
    row_w[pos] = w;
    inv_row[t0 * 2 + s] = pos;
  }
  __syncthreads();
  // parallel tile-map build: lane e of wave 0 writes expert e's entries
  if (wv == 0 && lane < 8) {
    int cnt = ctrl[lane];
    int n1 = (cnt + 255) >> 8, n2 = (cnt + 127) >> 7;
    int p1 = n1, p2 = n2;
    #pragma unroll
    for (int d = 1; d < 8; d <<= 1) {
      int v1 = __shfl_up(p1, d, 64);
      int v2 = __shfl_up(p2, d, 64);
      if (lane >= d) { p1 += v1; p2 += v2; }
    }
    int b1 = p1 - n1, b2 = p2 - n2;
    for (int m = 0; m < n1; ++m) tmap[b1 + m] = (lane << 8) | m;
    for (int m = 0; m < n2; ++m) tmap[128 + b2 + m] = (lane << 8) | m;
    if (lane == 7) { ctrl[16] = p1; ctrl[17] = p2; }
  }
}

// ====== grouped GEMM, BK=32 tiles, 4-deep rotation, ONE barrier/tile (R14) ======

#define KSTEP(T_, NT_) do {                                                \
    int buf_ = (T_) & 3;                                                   \
    WAITV8;                                                                \
    BARRIER;                                                               \
    int tc_ = imin((T_) + 3, (NT_) - 1);                                   \
    STG(tc_ & 3, tc_);                                                     \
    short8 av[8], bv[4];                                                   \
    _Pragma("unroll")                                                      \
    for (int n = 0; n < 4; ++n)                                            \
      bv[n] = *(const short8*)(&lds[buf_][1][0] + bOff + n * 512);         \
    _Pragma("unroll")                                                      \
    for (int m = 0; m < 8; ++m)                                            \
      av[m] = *(const short8*)(&lds[buf_][0][0] + aOff + m * 512);         \
    __builtin_amdgcn_s_setprio(1);                                         \
    _Pragma("unroll")                                                      \
    for (int m = 0; m < 8; ++m)                                            \
      _Pragma("unroll")                                                    \
      for (int n = 0; n < 4; ++n)                                          \
        acc[m][n] = __builtin_amdgcn_mfma_f32_16x16x32_bf16(av[m], bv[n], acc[m][n], 0, 0, 0); \
    __builtin_amdgcn_s_setprio(0);                                         \
    WAITL0;                                                                \
} while (0)

#define K_PIPELINE(NT_)                                                    \
  WAITV0;                                                                  \
  STG(0, 0); STG(1, 1); STG(2, 2);                                         \
  _Pragma("unroll 1")                                                      \
  for (int t = 0; t < (NT_); ++t) { KSTEP(t, (NT_)); }

// ---------------- GEMM1: 256x256 tile per block, dynamic tile map ----------------
__global__ __launch_bounds__(512, 1) void gemm1_kernel(
    const unsigned short* __restrict__ xbf,   // [T][1024]
    const unsigned short* __restrict__ w12t,  // [E][4096][1024], 16-row interleave
    const int* __restrict__ row_tok, const float* __restrict__ row_w,
    const int* __restrict__ ctrl, const int* __restrict__ tmap,
    unsigned short* __restrict__ G) {
  // grid 1152 = 72 ti * 16 nt; bid = ti*16+nt (16 nt blocks co-resident share A panel)
  int bid = blockIdx.x;
  int nt = bid & 15;
  int ti = bid >> 4;
  if (ti >= ctrl[16]) return;
  int pm = tmap[ti];
  int e = pm >> 8, mt = pm & 255;
  int cnt = ctrl[e];
  int off = ctrl[8 + e];

  __shared__ unsigned short lds[4][2][8192];  // [depth][A/B][256 rows * 32 K]

  int tid = threadIdx.x, lane = tid & 63;
  const unsigned short* w12e = w12t + (size_t)e * (4096 * 1024);

  int sr = tid >> 2;
  int cS8 = ((tid & 3) ^ ((sr >> 1) & 3)) * 8;
  const unsigned short* bQ0 = w12e + (size_t)(nt * 256 + sr) * 1024 + cS8;
  const unsigned short* bQ1 = w12e + (size_t)(nt * 256 + 128 + sr) * 1024 + cS8;

  int wid = tid >> 6, wr = wid >> 2, wc = wid & 3;
  int lr16 = lane & 15, hi = lane >> 4;
  int koff = (hi ^ ((lr16 >> 1) & 3)) * 8;
  int aOff = (wr * 128 + lr16) * 32 + koff;
  int bOff = (wc * 64 + lr16) * 32 + koff;

  int tokA = row_tok[off + imin(mt * 256 + sr, cnt - 1)];
  int tokB = row_tok[off + imin(mt * 256 + 128 + sr, cnt - 1)];
  const unsigned short* aQ0 = xbf + (size_t)tokA * 1024 + cS8;
  const unsigned short* aQ1 = xbf + (size_t)tokB * 1024 + cS8;

#define STG(SB, T_) do {                                                   \
    gload16(aQ0 + (T_) * 32, &lds[SB][0][0] + tid * 8);                    \
    gload16(aQ1 + (T_) * 32, &lds[SB][0][0] + 4096 + tid * 8);             \
    gload16(bQ0 + (T_) * 32, &lds[SB][1][0] + tid * 8);                    \
    gload16(bQ1 + (T_) * 32, &lds[SB][1][0] + 4096 + tid * 8); } while (0)

  f32x4 z = {0.f, 0.f, 0.f, 0.f};
  f32x4 acc[8][4];
  #pragma unroll
  for (int m = 0; m < 8; ++m)
    #pragma unroll
    for (int n = 0; n < 4; ++n) acc[m][n] = z;

  K_PIPELINE(32)

  // fused SwiGLU epilogue: frag pairs (0,1),(2,3) are (W1,W2) for same H cols
  #pragma unroll
  for (int m = 0; m < 8; ++m)
    #pragma unroll
    for (int jj = 0; jj < 4; ++jj) {
      int rl = mt * 256 + wr * 128 + m * 16 + hi * 4 + jj;
      if (rl < cnt) {
        float wrj = row_w[off + rl];
        size_t base = (size_t)(off + rl) * HDIM + nt * 128 + wc * 32 + lr16;
        float h1 = acc[m][0][jj], h2 = acc[m][1][jj];
        G[base] = f2bf((h1 / (1.f + __expf(-h1))) * h2 * wrj);
        h1 = acc[m][2][jj]; h2 = acc[m][3][jj];
        G[base + 16] = f2bf((h1 / (1.f + __expf(-h1))) * h2 * wrj);
      }
    }
#undef STG
}

// ---------------- GEMM2: 128x256 tile per block, dynamic tile map ----------------
__global__ __launch_bounds__(512, 1) void gemm2_kernel(
    const unsigned short* __restrict__ G,     // [16384][2048]
    const unsigned short* __restrict__ w3t,   // [E][1024][2048]
    const int* __restrict__ ctrl, const int* __restrict__ tmap,
    unsigned short* __restrict__ Y) {
  // grid 544 = 136 ti * 4 nt; bid = ti*4+nt.  tmap already offset to 128-map.
  int bid = blockIdx.x;
  int nt = bid & 3;
  int ti = bid >> 2;
  if (ti >= ctrl[17]) return;
  int pm = tmap[ti];
  int e = pm >> 8, mt = pm & 255;   // M=128 tile index
  int cnt = ctrl[e];
  int off = ctrl[8 + e];

  __shared__ unsigned short ldsA[4][4096];   // 128 rows * 32 K
  __shared__ unsigned short ldsB[4][8192];   // 256 rows * 32 K

  int tid = threadIdx.x, lane = tid & 63;
  const unsigned short* w3e = w3t + (size_t)e * (1024 * 2048);

  int sr = tid >> 2;
  int cS8 = ((tid & 3) ^ ((sr >> 1) & 3)) * 8;
  const unsigned short* bQ0 = w3e + (size_t)(nt * 256 + sr) * 2048 + cS8;
  const unsigned short* bQ1 = w3e + (size_t)(nt * 256 + 128 + sr) * 2048 + cS8;
  const unsigned short* aQ0 =
      G + (size_t)(off + imin(mt * 128 + sr, cnt - 1)) * 2048 + cS8;

  int wid = tid >> 6, wr = wid >> 2, wc = wid & 3;   // wr 0..1, wc 0..3
  int lr16 = lane & 15, hi = lane >> 4;
  int koff = (hi ^ ((lr16 >> 1) & 3)) * 8;
  int aOff = (wr * 64 + lr16) * 32 + koff;
  int bOff = (wc * 64 + lr16) * 32 + koff;

#define STG2(SB, T_) do {                                                  \
    gload16(aQ0 + (T_) * 32, &ldsA[SB][0] + tid * 8);                      \
    gload16(bQ0 + (T_) * 32, &ldsB[SB][0] + tid * 8);                      \
    gload16(bQ1 + (T_) * 32, &ldsB[SB][0] + 4096 + tid * 8); } while (0)

  f32x4 z = {0.f, 0.f, 0.f, 0.f};
  f32x4 acc[4][4];
  #pragma unroll
  for (int m = 0; m < 4; ++m)
    #pragma unroll
    for (int n = 0; n < 4; ++n) acc[m][n] = z;

  WAITV0;
  STG2(0, 0); STG2(1, 1); STG2(2, 2);
  #pragma unroll 1
  for (int t = 0; t < 64; ++t) {
    int buf = t & 3;
    WAITV6;
    BARRIER;
    int tc = imin(t + 3, 63);
    STG2(tc & 3, tc);
    short8 av[4], bv[4];
    #pragma unroll
    for (int n = 0; n < 4; ++n)
      bv[n] = *(const short8*)(&ldsB[buf][0] + bOff + n * 512);
    #pragma unroll
    for (int m = 0; m < 4; ++m)
      av[m] = *(const short8*)(&ldsA[buf][0] + aOff + m * 512);
    __builtin_amdgcn_s_setprio(1);
    #pragma unroll
    for (int m = 0; m < 4; ++m)
      #pragma unroll
      for (int n = 0; n < 4; ++n)
        acc[m][n] = __builtin_amdgcn_mfma_f32_16x16x32_bf16(av[m], bv[n], acc[m][n], 0, 0, 0);
    __builtin_amdgcn_s_setprio(0);
    WAITL0;
  }
#undef STG2

  #pragma unroll
  for (int m = 0; m < 4; ++m)
    #pragma unroll
    for (int jj = 0; jj < 4; ++jj) {
      int rl = mt * 128 + wr * 64 + m * 16 + hi * 4 + jj;
      if (rl < cnt) {
        size_t yrow = (size_t)(off + rl) * DDIM + nt * 256 + wc * 64 + lr16;
        #pragma unroll
        for (int n = 0; n < 4; ++n) Y[yrow + n * 16] = f2bf(acc[m][n][jj]);
      }
    }
}

// ---------------- combine: out[t] = Y[rowA] + Y[rowB] ----------------
__global__ __launch_bounds__(256) void combine_kernel(const unsigned short* __restrict__ Y,
                                                      const int* __restrict__ inv_row,
                                                      float* __restrict__ out) {
  int gid = blockIdx.x * 256 + threadIdx.x;   // 8192 * 128
  int t = gid >> 7;
  int cidx = (gid & 127) * 8;
  int rA = inv_row[t * 2], rB = inv_row[t * 2 + 1];
  uint4 va = *(const uint4*)(Y + (size_t)rA * DDIM + cidx);
  uint4 vb = *(const uint4*)(Y + (size_t)rB * DDIM + cidx);
  const unsigned short* pa = (const unsigned short*)&va;
  const unsigned short* pb = (const unsigned short*)&vb;
  float4 o0, o1;
  o0.x = bf2f(pa[0]) + bf2f(pb[0]); o0.y = bf2f(pa[1]) + bf2f(pb[1]);
  o0.z = bf2f(pa[2]) + bf2f(pb[2]); o0.w = bf2f(pa[3]) + bf2f(pb[3]);
  o1.x = bf2f(pa[4]) + bf2f(pb[4]); o1.y = bf2f(pa[5]) + bf2f(pb[5]);
  o1.z = bf2f(pa[6]) + bf2f(pb[6]); o1.w = bf2f(pa[7]) + bf2f(pb[7]);
  float* op = out + (size_t)t * DDIM + cidx;
  *(float4*)op = o0;
  *(float4*)(op + 4) = o1;
}

extern "C" void kernel_launch(void* const* d_in, const int* in_sizes, int n_in,
                              void* d_out, int out_size, void* d_ws, size_t ws_size,
                              hipStream_t stream) {
  const float* x  = (const float*)d_in[0];
  const float* gw = (const float*)d_in[1];
  const float* w1 = (const float*)d_in[2];
  const float* w2 = (const float*)d_in[3];
  const float* w3 = (const float*)d_in[4];
  float* out = (float*)d_out;
  char* ws = (char*)d_ws;

  // workspace layout (bytes); total ~218.4 MB
  unsigned short* xbf  = (unsigned short*)(ws + 0);             // 16,777,216
  unsigned short* w12t = (unsigned short*)(ws + 16777216);      // 67,108,864
  unsigned short* w3t  = (unsigned short*)(ws + 83886080);      // 33,554,432
  unsigned short* G    = (unsigned short*)(ws + 117440512);     // 67,108,864
  unsigned short* Y    = (unsigned short*)(ws + 184549376);     // 33,554,432
  int*   row_tok = (int*)  (ws + 218103808);
  float* row_w   = (float*)(ws + 218169344);
  int*   inv_row = (int*)  (ws + 218234880);
  int*   t_exp   = (int*)  (ws + 218300416);   // reused as tmap after partition
  float* t_w     = (float*)(ws + 218365952);
  int*   ctrl    = (int*)  (ws + 218431488);

  prep_kernel<<<14336, 256, 0, stream>>>(x, gw, w1, w2, w3, w12t, w3t,
                                         t_exp, t_w, xbf);
  partition_kernel<<<1, 1024, 0, stream>>>(t_exp, t_w, ctrl, row_tok, row_w,
                                           inv_row, t_exp);

  gemm1_kernel<<<1152, 512, 0, stream>>>(xbf, w12t, row_tok, row_w, ctrl, t_exp, G);
  gemm2_kernel<<<544, 512, 0, stream>>>(G, w3t, ctrl, t_exp + 128, Y);
  combine_kernel<<<4096, 256, 0, stream>>>(Y, inv_row, out);
}